// Round 11
// baseline (185.724 us; speedup 1.0000x reference)
//
#include <hip/hip_runtime.h>
#include <math.h>

// Problem constants: B=4, S=2048, D=512, H=8, Hd=64
#define SEQ 2048
#define DM 512
#define NH 8
#define HD 64

typedef _Float16 f16x8 __attribute__((ext_vector_type(8)));
typedef _Float16 f16x4 __attribute__((ext_vector_type(4)));
typedef __fp16 h16x2 __attribute__((ext_vector_type(2)));   // builtin ABI type
typedef float f32x4 __attribute__((ext_vector_type(4)));
#define MFMAH(A, B, C) __builtin_amdgcn_mfma_f32_16x16x32_f16(A, B, C, 0, 0, 0)

__device__ __forceinline__ void async16(const void* g, void* l) {
    __builtin_amdgcn_global_load_lds((__attribute__((address_space(1))) void*)g,
                                     (__attribute__((address_space(3))) void*)l,
                                     16, 0, 0);
}
#define LGKM0() asm volatile("s_waitcnt lgkmcnt(0)" ::: "memory")
#define WAITVM(n) asm volatile("s_waitcnt vmcnt(" #n ")" ::: "memory")
#define SB0() __builtin_amdgcn_sched_barrier(0)
// raw barrier (no implicit vmcnt/lgkmcnt drain) fenced against code motion
#define BAR() do { SB0(); __builtin_amdgcn_s_barrier(); SB0(); } while (0)

// native exp2 (scores bounded |s|<=~9: no edge cases, 1-ulp HW accuracy fine)
#if __has_builtin(__builtin_amdgcn_exp2f)
#define EXP2(x) __builtin_amdgcn_exp2f(x)
#else
#define EXP2(x) exp2f(x)
#endif

// scale = 1/sqrt(64) * log2(e), folded into q at the QKV epilogue;
// scores land in the log2 domain -> exp2, no max subtraction needed.
#define QSCALE 0.18033688011112042f

// ---------------------------------------------------------------------------
// Fused prep kernel (range-dispatched by blockIdx.x). Single-term fp16 W
// (validated R8: absmax unchanged at 9.77e-4).
// ---------------------------------------------------------------------------
__global__ __launch_bounds__(256)
void prep_all(const float* __restrict__ x, const float* __restrict__ Wqkv,
              const float* __restrict__ Wo,
              float2* __restrict__ tab,
              _Float16* __restrict__ wqt_h, _Float16* __restrict__ wot_h,
              _Float16* __restrict__ xh)
{
    __shared__ float T[64][65];
    const int bid = blockIdx.x;
    const int tid = threadIdx.x;

    if (bid < 256) {
        int idx = bid * 256 + tid;   // 65536
        int s = idx >> 5, p = idx & 31;
        const float c = -0.28782313662425572f;  // -ln(10000)/32
        float f = (float)s * expf(c * (float)p);
        float sn, cs;
        sincosf(f, &sn, &cs);
        tab[idx] = make_float2(cs, sn);
        return;
    }
    if (bid < 512) {
        const float* W;
        _Float16 *hi;
        int N, bx, by;
        if (bid < 448) {
            int b = bid - 256;                 // 192 blocks: 24 x 8
            bx = b % 24; by = b / 24;
            W = Wqkv; hi = wqt_h; N = 3 * DM;
        } else {
            int b = bid - 448;                 // 64 blocks: 8 x 8
            bx = b % 8; by = b / 8;
            W = Wo; hi = wot_h; N = DM;
        }
        const int c0 = bx * 64, k0 = by * 64;
#pragma unroll
        for (int it = 0; it < 4; ++it) {
            int idx = it * 256 + tid;
            int r = idx >> 4, c4 = (idx & 15) << 2;
            *(float4*)&T[r][c4] = *(const float4*)&W[(size_t)(k0 + r) * N + c0 + c4];
        }
        __syncthreads();
#pragma unroll
        for (int it = 0; it < 4; ++it) {
            int idx = it * 256 + tid;
            int c = idx >> 4, k4 = (idx & 15) << 2;
            f16x4 hv;
#pragma unroll
            for (int r = 0; r < 4; ++r)
                hv[r] = (_Float16)T[k4 + r][c];
            *(f16x4*)&hi[(size_t)(c0 + c) * DM + k0 + k4] = hv;
        }
        return;
    }
    // x -> fp16 single
    size_t i = ((size_t)(bid - 512) * 256 + tid) << 3;
    float4 a0 = *(const float4*)&x[i];
    float4 a1 = *(const float4*)&x[i + 4];
    float fv[8] = {a0.x, a0.y, a0.z, a0.w, a1.x, a1.y, a1.z, a1.w};
    f16x8 hv;
#pragma unroll
    for (int j = 0; j < 8; ++j) hv[j] = (_Float16)fv[j];
    *(f16x8*)&xh[i] = hv;
}

// ---------------------------------------------------------------------------
// Kernel 1: QKV GEMM, single-term fp16 MFMA, XCD row swizzle + dbuf counted
// vmcnt (R8/R9-validated). LDS 32 KB (2 bufs x (A 8K + B 8K)).
// ---------------------------------------------------------------------------
__global__ __launch_bounds__(256)
void qkv_mfma(const _Float16* __restrict__ xh,
              const _Float16* __restrict__ wth,
              const float* __restrict__ bias, const float2* __restrict__ tab,
              _Float16* __restrict__ qo, _Float16* __restrict__ ko,
              _Float16* __restrict__ vo)
{
    __shared__ __align__(16) _Float16 SM[16384];    // 32 KB: [buf][A|B]

    const int tid  = threadIdx.x;
    const int lane = tid & 63;
    const int wave = tid >> 6;
    const int quad = lane >> 4;
    const int m    = lane & 15;
    const int wr   = wave >> 1, wc = wave & 1;

    // swizzle: linear id -> (rowblk, by) with row-colocation per XCD
    const int linear = blockIdx.x + (blockIdx.y << 6);   // 0..767
    const int xcd = linear & 7;
    const int r   = linear >> 3;                         // 0..95
    const int row0 = ((xcd << 3) + r / 12) * 128;
    const int by   = r % 12;
    const int col0 = by * 128;

    const size_t aoff0 = (size_t)(row0 + wave * 16 + m) * DM + (quad << 3);
    const size_t aoff1 = (size_t)(row0 + (wave + 4) * 16 + m) * DM + (quad << 3);
    const size_t boff0 = (size_t)(col0 + wave * 16 + m) * DM + (quad << 3);
    const size_t boff1 = (size_t)(col0 + (wave + 4) * 16 + m) * DM + (quad << 3);

    f32x4 acc[4][4];
#pragma unroll
    for (int i = 0; i < 4; ++i)
#pragma unroll
        for (int j = 0; j < 4; ++j) acc[i][j] = (f32x4){0.f, 0.f, 0.f, 0.f};

#define QSTAGE(b, kk) do {                                                    \
        async16(xh + aoff0 + (kk), &SM[((b) << 13) + (wave << 9)]);           \
        async16(xh + aoff1 + (kk), &SM[((b) << 13) + ((wave + 4) << 9)]);     \
        async16(wth + boff0 + (kk), &SM[((b) << 13) + 4096 + (wave << 9)]);   \
        async16(wth + boff1 + (kk), &SM[((b) << 13) + 4096 + ((wave + 4) << 9)]); \
    } while (0)

    QSTAGE(0, 0);
#pragma unroll 1
    for (int k0 = 0; k0 < DM; k0 += 32) {
        const int b = (k0 >> 5) & 1;
        if (k0 + 32 < DM) { QSTAGE(b ^ 1, k0 + 32); WAITVM(4); }
        else              { WAITVM(0); }
        BAR();

        const _Float16* Ah = &SM[b << 13];
        const _Float16* Bh = Ah + 4096;
        f16x8 av[4], bvh[4];
#pragma unroll
        for (int t = 0; t < 4; ++t) {
            int ai  = ((((wr << 2) + t) << 6) + lane) << 3;
            int bi2 = ((((wc << 2) + t) << 6) + lane) << 3;
            av[t]  = *(const f16x8*)&Ah[ai];
            bvh[t] = *(const f16x8*)&Bh[bi2];
        }
#pragma unroll
        for (int rt = 0; rt < 4; ++rt)
#pragma unroll
            for (int ct = 0; ct < 4; ++ct)
                acc[rt][ct] = MFMAH(av[rt], bvh[ct], acc[rt][ct]);
        LGKM0();
        BAR();
    }
#undef QSTAGE

    // ---- epilogue ----
    const int sel   = by >> 2;              // 0=q 1=k 2=v
    const int head  = ((by << 1) + wc) & 7;
    const int row0w = row0 + wr * 64;
    const int bidx  = row0w >> 11;
    const int s0    = row0w & (SEQ - 1);
    const int colw  = col0 + wc * 64;

    float bc[4];
#pragma unroll
    for (int ct = 0; ct < 4; ++ct) bc[ct] = bias[colw + (ct << 4) + m];

    if (sel == 2) {
        // v: direct transposed store [B,H,d,s], f16x4 along s
#pragma unroll
        for (int ct = 0; ct < 4; ++ct) {
            int d = (ct << 4) + m;
#pragma unroll
            for (int rt = 0; rt < 4; ++rt) {
                f32x4 a = acc[rt][ct];
                f16x4 ov;
#pragma unroll
                for (int rg = 0; rg < 4; ++rg) ov[rg] = (_Float16)(a[rg] + bc[ct]);
                size_t off = ((size_t)((bidx * NH + head) * HD + d)) * SEQ
                           + s0 + (rt << 4) + (quad << 2);
                *(f16x4*)&vo[off] = ov;
            }
        }
    } else {
        // q/k: per-wave LDS transpose + RoPE + fp16 vector stores
        const float sc = (sel == 0) ? QSCALE : 1.0f;
        _Float16* dh = (sel == 0) ? qo : ko;
        float* tb = (float*)SM + wave * 1088;       // 16 x 68 f32 (17.4KB < 32KB)
        const int rr = lane >> 2, jj = lane & 3;
#pragma unroll
        for (int rt = 0; rt < 4; ++rt) {
#pragma unroll
            for (int ct = 0; ct < 4; ++ct)
#pragma unroll
                for (int rg = 0; rg < 4; ++rg)
                    tb[((quad << 2) + rg) * 68 + (ct << 4) + m] =
                        acc[rt][ct][rg] + bc[ct];
            LGKM0();
            int s = (row0w + (rt << 4) + rr) & (SEQ - 1);
#pragma unroll
            for (int i = 0; i < 4; ++i) {
                int c = (jj << 2) + (i << 4);
                float4 vv = *(const float4*)&tb[rr * 68 + c];
                float4 t4 = *(const float4*)&tab[(s << 5) + (c >> 1)];
                f16x4 hv;
                hv[0] = (_Float16)((vv.x * t4.x - vv.y * t4.y) * sc);
                hv[1] = (_Float16)((vv.x * t4.y + vv.y * t4.x) * sc);
                hv[2] = (_Float16)((vv.z * t4.z - vv.w * t4.w) * sc);
                hv[3] = (_Float16)((vv.z * t4.w + vv.w * t4.z) * sc);
                size_t off = (((size_t)(bidx * NH + head) * SEQ + s) << 6) + c;
                *(f16x4*)&dh[off] = hv;
            }
        }
    }
}

// ---------------------------------------------------------------------------
// Kernel 2: fp16 MFMA flash attention — R11: 256 q/block, 64 q/wave
// (4 groups), grid 256 blocks (1/CU). Mechanism (R7-validated scaling):
// every K/V LDS fragment read is shared by 4 q-group MFMAs -> per-q LDS
// traffic halves vs R10 (384 cyc/tile/wave for 64 q vs 336 for 32 q);
// per-CU LDS floor 4 waves x 32 tiles x 384 ~ 49K cyc ~ 20.5 µs.
// Rotation fixed to full bijection: rot = 8*(m&7) + 32*(m>>3) -> write
// banks 2-way (free, was 4-way in R10), A-frag runs stay 8-contiguous
// (single ds_read_b128). Super-tile dbuf + counted vmcnt kept (no
// cross-block TLP at 1 block/CU). LDS 96 KB = 32K KH + 32K VF + 32K PW.
// ---------------------------------------------------------------------------
__global__ __launch_bounds__(256, 1)
void attn_mfma(const _Float16* __restrict__ qh_, const _Float16* __restrict__ kh_,
               const _Float16* __restrict__ vt, _Float16* __restrict__ oh)
{
    __shared__ __align__(16) _Float16 KH[2][8192];  // 2 bufs x super-tile (16 KB)
    __shared__ __align__(16) _Float16 VF[2][8192];
    __shared__ __align__(16) _Float16 PW[4][4096];  // per wave 4 x (16 x 64)

    const int tid  = threadIdx.x;
    const int lane = tid & 63;
    const int wave = tid >> 6;
    const int m    = lane & 15;
    const int quad = lane >> 4;

    // XCD-bijective swizzle: 256 blocks, xcd = linear&7 (round-robin);
    // bh = xcd + 8*(idx>>3): each XCD hosts 4 bh x 8 q-tiles (K/V 2MB < L2).
    const int linear = blockIdx.x + (blockIdx.y << 3);   // 0..255
    const int xcd = linear & 7;
    const int idx = linear >> 3;                         // 0..31
    const int bh  = xcd + ((idx >> 3) << 3);             // 0..31
    const int qt  = idx & 7;                             // 0..7 (256-q tiles)
    const int bi = bh >> 3, h = bh & 7;

    const _Float16* qhp = qh_ + ((size_t)bh * SEQ + qt * 256 + wave * 64) * HD;
    const _Float16* khp = kh_ + (size_t)bh * SEQ * HD;
    const _Float16* vp  = vt  + (size_t)bh * HD * SEQ;

    // Q B-frags, four groups 16 rows apart (pre-scaled by QSCALE)
    f16x8 qf[4][2];
#pragma unroll
    for (int g = 0; g < 4; ++g)
#pragma unroll
        for (int c = 0; c < 2; ++c)
            qf[g][c] = *(const f16x8*)&qhp[g * 1024 + ((size_t)m << 6)
                                           + c * 32 + (quad << 3)];

    f32x4 oacc[4][4];   // [g][dt]: D[q=quad*4+rg][d=dt*16+m]
#pragma unroll
    for (int g = 0; g < 4; ++g)
#pragma unroll
        for (int dt = 0; dt < 4; ++dt) oacc[g][dt] = (f32x4){0.f, 0.f, 0.f, 0.f};
    float l1[4] = {0.f, 0.f, 0.f, 0.f}, l2[4] = {0.f, 0.f, 0.f, 0.f};

    // staging offsets: wave w stages K keys w*16+m and V rows d=w*16+m
    const size_t koff0 = ((size_t)(wave * 16 + m) << 6) + (quad << 3);
    const size_t koff1 = koff0 + 32;
    const size_t voff0 = ((size_t)(wave * 16 + m) << 11) + (quad << 3);
    const size_t voff1 = voff0 + 32;

    const h16x2 ones = {(__fp16)1.f, (__fp16)1.f};
    _Float16* pw = PW[wave];
    const int rot = ((m & 7) << 3) + ((m >> 3) << 5);  // bijective, 8-granular

    auto tile = [&](const _Float16* KB, const _Float16* VB) {
        // ---- per-nt: QK for all 4 groups (kf read ONCE) + fused softmax ----
#pragma unroll
        for (int nt = 0; nt < 4; ++nt) {
            f32x4 sv[4];
#pragma unroll
            for (int g = 0; g < 4; ++g) sv[g] = (f32x4){0.f, 0.f, 0.f, 0.f};
#pragma unroll
            for (int c = 0; c < 2; ++c) {
                f16x8 kf = *(const f16x8*)&KB[((c * 4 + nt) * 64 + lane) << 3];
#pragma unroll
                for (int g = 0; g < 4; ++g)
                    sv[g] = MFMAH(kf, qf[g][c], sv[g]);
            }
            // sv[g]: [key=nt*16+quad*4+rg][q=m], log2 domain
#pragma unroll
            for (int g = 0; g < 4; ++g) {
                union { unsigned int u[2]; f16x4 v; } pk;
#pragma unroll
                for (int i = 0; i < 2; ++i) {
                    h16x2 t = __builtin_amdgcn_cvt_pkrtz(EXP2(sv[g][2 * i]),
                                                         EXP2(sv[g][2 * i + 1]));
                    if (i == 0) l1[g] = __builtin_amdgcn_fdot2(t, ones, l1[g], false);
                    else        l2[g] = __builtin_amdgcn_fdot2(t, ones, l2[g], false);
                    union { h16x2 hh; unsigned int uu; } cv; cv.hh = t;
                    pk.u[i] = cv.uu;
                }
                int pos = ((nt << 4) + (quad << 2) + rot) & 63;
                *(f16x4*)&pw[g * 1024 + (m << 6) + pos] = pk.v;
            }
        }

        // ---- V to regs (read ONCE, feeds all 4 groups' PV) ----
        f16x8 vr0[4], vr1[4];
#pragma unroll
        for (int dt = 0; dt < 4; ++dt) {
            vr0[dt] = *(const f16x8*)&VB[((0 * 4 + dt) * 64 + lane) << 3];
            vr1[dt] = *(const f16x8*)&VB[((1 * 4 + dt) * 64 + lane) << 3];
        }
        LGKM0();

        // ---- PV per group; A-frags are single b128 (8-contiguous runs) ----
#pragma unroll
        for (int g = 0; g < 4; ++g) {
            f16x8 pf0 = *(const f16x8*)&pw[g * 1024 + (m << 6)
                                           + (((quad << 3) + rot) & 63)];
            f16x8 pf1 = *(const f16x8*)&pw[g * 1024 + (m << 6)
                                           + ((32 + (quad << 3) + rot) & 63)];
#pragma unroll
            for (int dt = 0; dt < 4; ++dt) {
                oacc[g][dt] = MFMAH(pf0, vr0[dt], oacc[g][dt]);
                oacc[g][dt] = MFMAH(pf1, vr1[dt], oacc[g][dt]);
            }
        }
    };

#define STAGE(b, st_) do { const size_t t0 = (size_t)(st_) * 2;               \
        async16(khp + koff0 + (t0 << 12), &KH[b][wave << 9]);                 \
        async16(khp + koff1 + (t0 << 12), &KH[b][(wave + 4) << 9]);           \
        async16(khp + koff0 + ((t0 + 1) << 12), &KH[b][4096 + (wave << 9)]);  \
        async16(khp + koff1 + ((t0 + 1) << 12), &KH[b][4096 + ((wave + 4) << 9)]); \
        async16(vp + voff0 + (t0 << 6), &VF[b][wave << 9]);                   \
        async16(vp + voff1 + (t0 << 6), &VF[b][(wave + 4) << 9]);             \
        async16(vp + voff0 + ((t0 + 1) << 6), &VF[b][4096 + (wave << 9)]);    \
        async16(vp + voff1 + ((t0 + 1) << 6), &VF[b][4096 + ((wave + 4) << 9)]); \
    } while (0)

    // ---- main loop: 16 super-tiles, double-buffered, counted vmcnt ----
    STAGE(0, 0);
#pragma unroll 1
    for (int st = 0; st < SEQ / 128; ++st) {
        const int b = st & 1;
        if (st + 1 < SEQ / 128) { STAGE(b ^ 1, st + 1); WAITVM(8); }
        else                    { WAITVM(0); }
        BAR();                       // super-tile st landed for all waves
        tile(&KH[b][0], &VF[b][0]);
        tile(&KH[b][4096], &VF[b][4096]);
        LGKM0();                     // my ds reads of buf b retired
        BAR();                       // everyone done -> b restageable
    }
#undef STAGE

    // ---- epilogue: per-group l reduce, normalize, fp16 store ----
#pragma unroll
    for (int g = 0; g < 4; ++g) {
        float lr = l1[g] + l2[g];
        lr += __shfl_xor(lr, 16);
        lr += __shfl_xor(lr, 32);
        float inv = 1.0f / lr;
        size_t ob = ((size_t)(bi * SEQ + qt * 256 + wave * 64 + g * 16
                              + (quad << 2))) * DM + h * HD + m;
#pragma unroll
        for (int rg = 0; rg < 4; ++rg) {
            float il = __shfl(inv, (quad << 2) + rg, 16);
#pragma unroll
            for (int dt = 0; dt < 4; ++dt)
                oh[ob + (size_t)rg * DM + dt * 16] =
                    (_Float16)(oacc[g][dt][rg] * il);
        }
    }
}

// ---------------------------------------------------------------------------
// Kernel 3: out = attn @ Wo + bo, single-term fp16 MFMA + XCD row swizzle
// + dbuf counted vmcnt (R10-validated). LDS 32 KB.
// ---------------------------------------------------------------------------
__global__ __launch_bounds__(256)
void out_mfma(const _Float16* __restrict__ ah,
              const _Float16* __restrict__ wth,
              const float* __restrict__ bias, float* __restrict__ out)
{
    __shared__ __align__(16) _Float16 SM[16384];    // 32 KB: [buf][A|B]

    const int tid  = threadIdx.x;
    const int lane = tid & 63;
    const int wave = tid >> 6;
    const int quad = lane >> 4;
    const int m    = lane & 15;
    const int wr   = wave >> 1, wc = wave & 1;

    // swizzle: XCD x owns row-blocks 8x..8x+7 (A slice 1MB + Wo-hi 0.5MB in L2)
    const int linear = blockIdx.x + (blockIdx.y << 6);   // 0..255
    const int xcd = linear & 7;
    const int r   = linear >> 3;                         // 0..31
    const int row0 = ((xcd << 3) + (r >> 2)) * 128;
    const int col0 = (r & 3) * 128;

    const size_t aoff0 = (size_t)(row0 + wave * 16 + m) * DM + (quad << 3);
    const size_t aoff1 = (size_t)(row0 + (wave + 4) * 16 + m) * DM + (quad << 3);
    const size_t boff0 = (size_t)(col0 + wave * 16 + m) * DM + (quad << 3);
    const size_t boff1 = (size_t)(col0 + (wave + 4) * 16 + m) * DM + (quad << 3);

    f32x4 acc[4][4];
#pragma unroll
    for (int i = 0; i < 4; ++i)
#pragma unroll
        for (int j = 0; j < 4; ++j) acc[i][j] = (f32x4){0.f, 0.f, 0.f, 0.f};

#define OSTAGE(b, kk) do {                                                    \
        async16(ah + aoff0 + (kk), &SM[((b) << 13) + (wave << 9)]);           \
        async16(ah + aoff1 + (kk), &SM[((b) << 13) + ((wave + 4) << 9)]);     \
        async16(wth + boff0 + (kk), &SM[((b) << 13) + 4096 + (wave << 9)]);   \
        async16(wth + boff1 + (kk), &SM[((b) << 13) + 4096 + ((wave + 4) << 9)]); \
    } while (0)

    OSTAGE(0, 0);
#pragma unroll 1
    for (int k0 = 0; k0 < DM; k0 += 32) {
        const int b = (k0 >> 5) & 1;
        if (k0 + 32 < DM) { OSTAGE(b ^ 1, k0 + 32); WAITVM(4); }
        else              { WAITVM(0); }
        BAR();

        const _Float16* Ah = &SM[b << 13];
        const _Float16* Bh = Ah + 4096;
        f16x8 av[4], bvh[4];
#pragma unroll
        for (int t = 0; t < 4; ++t) {
            int ai  = ((((wr << 2) + t) << 6) + lane) << 3;
            int bi2 = ((((wc << 2) + t) << 6) + lane) << 3;
            av[t]  = *(const f16x8*)&Ah[ai];
            bvh[t] = *(const f16x8*)&Bh[bi2];
        }
#pragma unroll
        for (int rt = 0; rt < 4; ++rt)
#pragma unroll
            for (int ct = 0; ct < 4; ++ct)
                acc[rt][ct] = MFMAH(av[rt], bvh[ct], acc[rt][ct]);
        LGKM0();
        BAR();
    }
#undef OSTAGE

    // epilogue: LDS transpose -> coalesced float4 stores
    const int row0w = row0 + wr * 64;
    const int colw  = col0 + wc * 64;
    float bc[4];
#pragma unroll
    for (int ct = 0; ct < 4; ++ct) bc[ct] = bias[colw + (ct << 4) + m];

    float* tb = (float*)SM + wave * 1088;
    const int rr = lane >> 2, jj = lane & 3;
#pragma unroll
    for (int rt = 0; rt < 4; ++rt) {
#pragma unroll
        for (int ct = 0; ct < 4; ++ct)
#pragma unroll
            for (int rg = 0; rg < 4; ++rg)
                tb[((quad << 2) + rg) * 68 + (ct << 4) + m] =
                    acc[rt][ct][rg] + bc[ct];
        LGKM0();
        int n = row0w + (rt << 4) + rr;
#pragma unroll
        for (int i = 0; i < 4; ++i) {
            int c = (jj << 2) + (i << 4);
            *(float4*)&out[(size_t)n * DM + colw + c] =
                *(const float4*)&tb[rr * 68 + c];
        }
    }
}

// ---------------------------------------------------------------------------
extern "C" void kernel_launch(void* const* d_in, const int* in_sizes, int n_in,
                              void* d_out, int out_size, void* d_ws, size_t ws_size,
                              hipStream_t stream)
{
    const float* x    = (const float*)d_in[0];
    const float* Wqkv = (const float*)d_in[1];
    const float* bqkv = (const float*)d_in[2];
    const float* Wo   = (const float*)d_in[3];
    const float* bo   = (const float*)d_in[4];
    float* out = (float*)d_out;

    char* ws = (char*)d_ws;
    const size_t MB = 1024 * 1024;
    _Float16* qh    = (_Float16*)(ws);                       // 8 MB [B,H,S,64]
    _Float16* oh    = (_Float16*)(ws + 8 * MB);              // 8 MB [B,S,512]
    _Float16* kh    = (_Float16*)(ws + 16 * MB);             // 8 MB [B,H,S,64]
    _Float16* vT    = (_Float16*)(ws + 24 * MB);             // 8 MB [B,H,64,S]
    _Float16* xh    = (_Float16*)(ws + 32 * MB);             // 8 MB [8192][512]
    _Float16* wqt_h = (_Float16*)(ws + 40 * MB);             // 1.5 MB [1536][512]
    _Float16* wot_h = (_Float16*)(ws + 42 * MB);             // 0.5 MB [512][512]
    float2*   rtab  = (float2*)(ws + 43 * MB);               // 0.5 MB [2048][32]

    prep_all<<<2560, 256, 0, stream>>>(x, Wqkv, Wo, rtab, wqt_h, wot_h, xh);
    qkv_mfma<<<dim3(64, 12), 256, 0, stream>>>(xh, wqt_h, bqkv, rtab,
                                               qh, kh, vT);
    attn_mfma<<<dim3(8, 32), 256, 0, stream>>>(qh, kh, vT, oh);
    out_mfma<<<dim3(64, 4), 256, 0, stream>>>(oh, wot_h, bo, out);
}

// Round 12
// 164.997 us; speedup vs baseline: 1.1256x; 1.1256x over previous
//
#include <hip/hip_runtime.h>
#include <math.h>

// Problem constants: B=4, S=2048, D=512, H=8, Hd=64
#define SEQ 2048
#define DM 512
#define NH 8
#define HD 64

typedef _Float16 f16x8 __attribute__((ext_vector_type(8)));
typedef _Float16 f16x4 __attribute__((ext_vector_type(4)));
typedef __fp16 h16x2 __attribute__((ext_vector_type(2)));   // builtin ABI type
typedef float f32x4 __attribute__((ext_vector_type(4)));
#define MFMAH(A, B, C) __builtin_amdgcn_mfma_f32_16x16x32_f16(A, B, C, 0, 0, 0)

__device__ __forceinline__ void async16(const void* g, void* l) {
    __builtin_amdgcn_global_load_lds((__attribute__((address_space(1))) void*)g,
                                     (__attribute__((address_space(3))) void*)l,
                                     16, 0, 0);
}
#define LGKM0() asm volatile("s_waitcnt lgkmcnt(0)" ::: "memory")
#define WAITVM(n) asm volatile("s_waitcnt vmcnt(" #n ")" ::: "memory")
#define SB0() __builtin_amdgcn_sched_barrier(0)
// raw barrier (no implicit vmcnt/lgkmcnt drain) fenced against code motion
#define BAR() do { SB0(); __builtin_amdgcn_s_barrier(); SB0(); } while (0)

// native exp2 (scores bounded |s|<=~9: no edge cases, 1-ulp HW accuracy fine)
#if __has_builtin(__builtin_amdgcn_exp2f)
#define EXP2(x) __builtin_amdgcn_exp2f(x)
#else
#define EXP2(x) exp2f(x)
#endif

// scale = 1/sqrt(64) * log2(e), folded into q at the QKV epilogue;
// scores land in the log2 domain -> exp2, no max subtraction needed.
#define QSCALE 0.18033688011112042f

// ---------------------------------------------------------------------------
// Fused prep kernel (range-dispatched by blockIdx.x). Single-term fp16 W
// (validated R8: absmax unchanged at 9.77e-4).
// ---------------------------------------------------------------------------
__global__ __launch_bounds__(256)
void prep_all(const float* __restrict__ x, const float* __restrict__ Wqkv,
              const float* __restrict__ Wo,
              float2* __restrict__ tab,
              _Float16* __restrict__ wqt_h, _Float16* __restrict__ wot_h,
              _Float16* __restrict__ xh)
{
    __shared__ float T[64][65];
    const int bid = blockIdx.x;
    const int tid = threadIdx.x;

    if (bid < 256) {
        int idx = bid * 256 + tid;   // 65536
        int s = idx >> 5, p = idx & 31;
        const float c = -0.28782313662425572f;  // -ln(10000)/32
        float f = (float)s * expf(c * (float)p);
        float sn, cs;
        sincosf(f, &sn, &cs);
        tab[idx] = make_float2(cs, sn);
        return;
    }
    if (bid < 512) {
        const float* W;
        _Float16 *hi;
        int N, bx, by;
        if (bid < 448) {
            int b = bid - 256;                 // 192 blocks: 24 x 8
            bx = b % 24; by = b / 24;
            W = Wqkv; hi = wqt_h; N = 3 * DM;
        } else {
            int b = bid - 448;                 // 64 blocks: 8 x 8
            bx = b % 8; by = b / 8;
            W = Wo; hi = wot_h; N = DM;
        }
        const int c0 = bx * 64, k0 = by * 64;
#pragma unroll
        for (int it = 0; it < 4; ++it) {
            int idx = it * 256 + tid;
            int r = idx >> 4, c4 = (idx & 15) << 2;
            *(float4*)&T[r][c4] = *(const float4*)&W[(size_t)(k0 + r) * N + c0 + c4];
        }
        __syncthreads();
#pragma unroll
        for (int it = 0; it < 4; ++it) {
            int idx = it * 256 + tid;
            int c = idx >> 4, k4 = (idx & 15) << 2;
            f16x4 hv;
#pragma unroll
            for (int r = 0; r < 4; ++r)
                hv[r] = (_Float16)T[k4 + r][c];
            *(f16x4*)&hi[(size_t)(c0 + c) * DM + k0 + k4] = hv;
        }
        return;
    }
    // x -> fp16 single
    size_t i = ((size_t)(bid - 512) * 256 + tid) << 3;
    float4 a0 = *(const float4*)&x[i];
    float4 a1 = *(const float4*)&x[i + 4];
    float fv[8] = {a0.x, a0.y, a0.z, a0.w, a1.x, a1.y, a1.z, a1.w};
    f16x8 hv;
#pragma unroll
    for (int j = 0; j < 8; ++j) hv[j] = (_Float16)fv[j];
    *(f16x8*)&xh[i] = hv;
}

// ---------------------------------------------------------------------------
// Kernel 1: QKV GEMM, single-term fp16 MFMA, XCD row swizzle. R12: 3-stage
// staging pipeline (2-deep prefetch) — R9's 1-deep only covered ~250cy of
// the ~200-300cy L2 latency; 2-deep gives ~500cy cover. LDS 48 KB
// (3 bufs x 16 KB), still 3 blocks/CU. vmcnt ledger: steady 12 outstanding
// -> WAITVM(8) drains the oldest stage; tail WAITVM(4)/WAITVM(0).
// ---------------------------------------------------------------------------
__global__ __launch_bounds__(256)
void qkv_mfma(const _Float16* __restrict__ xh,
              const _Float16* __restrict__ wth,
              const float* __restrict__ bias, const float2* __restrict__ tab,
              _Float16* __restrict__ qo, _Float16* __restrict__ ko,
              _Float16* __restrict__ vo)
{
    __shared__ __align__(16) _Float16 SM[24576];    // 48 KB: 3 x [A 8K|B 8K]

    const int tid  = threadIdx.x;
    const int lane = tid & 63;
    const int wave = tid >> 6;
    const int quad = lane >> 4;
    const int m    = lane & 15;
    const int wr   = wave >> 1, wc = wave & 1;

    // swizzle: linear id -> (rowblk, by) with row-colocation per XCD
    const int linear = blockIdx.x + (blockIdx.y << 6);   // 0..767
    const int xcd = linear & 7;
    const int r   = linear >> 3;                         // 0..95
    const int row0 = ((xcd << 3) + r / 12) * 128;
    const int by   = r % 12;
    const int col0 = by * 128;

    const size_t aoff0 = (size_t)(row0 + wave * 16 + m) * DM + (quad << 3);
    const size_t aoff1 = (size_t)(row0 + (wave + 4) * 16 + m) * DM + (quad << 3);
    const size_t boff0 = (size_t)(col0 + wave * 16 + m) * DM + (quad << 3);
    const size_t boff1 = (size_t)(col0 + (wave + 4) * 16 + m) * DM + (quad << 3);

    f32x4 acc[4][4];
#pragma unroll
    for (int i = 0; i < 4; ++i)
#pragma unroll
        for (int j = 0; j < 4; ++j) acc[i][j] = (f32x4){0.f, 0.f, 0.f, 0.f};

#define QSTAGE(b, kk) do {                                                    \
        async16(xh + aoff0 + (kk), &SM[(b) * 8192 + (wave << 9)]);            \
        async16(xh + aoff1 + (kk), &SM[(b) * 8192 + ((wave + 4) << 9)]);      \
        async16(wth + boff0 + (kk), &SM[(b) * 8192 + 4096 + (wave << 9)]);    \
        async16(wth + boff1 + (kk), &SM[(b) * 8192 + 4096 + ((wave + 4) << 9)]); \
    } while (0)

    QSTAGE(0, 0);
    QSTAGE(1, 32);
#pragma unroll 1
    for (int k0 = 0; k0 < DM; k0 += 32) {
        const int b = (k0 >> 5) % 3;
        if (k0 + 64 < DM)      { QSTAGE((b + 2) % 3, k0 + 64); WAITVM(8); }
        else if (k0 + 32 < DM) { WAITVM(4); }
        else                   { WAITVM(0); }
        BAR();

        const _Float16* Ah = &SM[b * 8192];
        const _Float16* Bh = Ah + 4096;
        f16x8 av[4], bvh[4];
#pragma unroll
        for (int t = 0; t < 4; ++t) {
            int ai  = ((((wr << 2) + t) << 6) + lane) << 3;
            int bi2 = ((((wc << 2) + t) << 6) + lane) << 3;
            av[t]  = *(const f16x8*)&Ah[ai];
            bvh[t] = *(const f16x8*)&Bh[bi2];
        }
#pragma unroll
        for (int rt = 0; rt < 4; ++rt)
#pragma unroll
            for (int ct = 0; ct < 4; ++ct)
                acc[rt][ct] = MFMAH(av[rt], bvh[ct], acc[rt][ct]);
        LGKM0();
        BAR();
    }
#undef QSTAGE

    // ---- epilogue ----
    const int sel   = by >> 2;              // 0=q 1=k 2=v
    const int head  = ((by << 1) + wc) & 7;
    const int row0w = row0 + wr * 64;
    const int bidx  = row0w >> 11;
    const int s0    = row0w & (SEQ - 1);
    const int colw  = col0 + wc * 64;

    float bc[4];
#pragma unroll
    for (int ct = 0; ct < 4; ++ct) bc[ct] = bias[colw + (ct << 4) + m];

    if (sel == 2) {
        // v: direct transposed store [B,H,d,s], f16x4 along s
#pragma unroll
        for (int ct = 0; ct < 4; ++ct) {
            int d = (ct << 4) + m;
#pragma unroll
            for (int rt = 0; rt < 4; ++rt) {
                f32x4 a = acc[rt][ct];
                f16x4 ov;
#pragma unroll
                for (int rg = 0; rg < 4; ++rg) ov[rg] = (_Float16)(a[rg] + bc[ct]);
                size_t off = ((size_t)((bidx * NH + head) * HD + d)) * SEQ
                           + s0 + (rt << 4) + (quad << 2);
                *(f16x4*)&vo[off] = ov;
            }
        }
    } else {
        // q/k: per-wave LDS transpose + RoPE + fp16 vector stores
        const float sc = (sel == 0) ? QSCALE : 1.0f;
        _Float16* dh = (sel == 0) ? qo : ko;
        float* tb = (float*)SM + wave * 1088;       // 16 x 68 f32 (17.4KB < 48KB)
        const int rr = lane >> 2, jj = lane & 3;
#pragma unroll
        for (int rt = 0; rt < 4; ++rt) {
#pragma unroll
            for (int ct = 0; ct < 4; ++ct)
#pragma unroll
                for (int rg = 0; rg < 4; ++rg)
                    tb[((quad << 2) + rg) * 68 + (ct << 4) + m] =
                        acc[rt][ct][rg] + bc[ct];
            LGKM0();
            int s = (row0w + (rt << 4) + rr) & (SEQ - 1);
#pragma unroll
            for (int i = 0; i < 4; ++i) {
                int c = (jj << 2) + (i << 4);
                float4 vv = *(const float4*)&tb[rr * 68 + c];
                float4 t4 = *(const float4*)&tab[(s << 5) + (c >> 1)];
                f16x4 hv;
                hv[0] = (_Float16)((vv.x * t4.x - vv.y * t4.y) * sc);
                hv[1] = (_Float16)((vv.x * t4.y + vv.y * t4.x) * sc);
                hv[2] = (_Float16)((vv.z * t4.z - vv.w * t4.w) * sc);
                hv[3] = (_Float16)((vv.z * t4.w + vv.w * t4.z) * sc);
                size_t off = (((size_t)(bidx * NH + head) * SEQ + s) << 6) + c;
                *(f16x4*)&dh[off] = hv;
            }
        }
    }
}

// ---------------------------------------------------------------------------
// Kernel 2: fp16 MFMA flash attention — EXACT R10 revert (best measured:
// 55.2 µs). 128 q/block, 32 q/wave (2 groups), 2 blocks/CU (the minimum
// 2 waves/SIMD for TLP — R11's 4-group/1-block-per-CU exposed the serial
// chain and regressed to 67.5). Super-tile dbuf + counted vmcnt; PW
// rotation gran-8 (single b128 A-frag reads). LDS 80 KB.
// ---------------------------------------------------------------------------
__global__ __launch_bounds__(256, 2)
void attn_mfma(const _Float16* __restrict__ qh_, const _Float16* __restrict__ kh_,
               const _Float16* __restrict__ vt, _Float16* __restrict__ oh)
{
    __shared__ __align__(16) _Float16 KH[2][8192];  // 2 bufs x super-tile (16 KB)
    __shared__ __align__(16) _Float16 VF[2][8192];
    __shared__ __align__(16) _Float16 PW[4][2048];  // per wave 2 x (16 x 64)

    const int tid  = threadIdx.x;
    const int lane = tid & 63;
    const int wave = tid >> 6;
    const int m    = lane & 15;
    const int quad = lane >> 4;

    // XCD-bijective swizzle: 512 blocks, xcd = linear&7 (round-robin);
    // bh = xcd + 8*(idx>>4): each XCD hosts 4 bh x 16 q-tiles.
    const int l   = blockIdx.x + (blockIdx.y << 4);
    const int idx = l >> 3;
    const int bh  = (l & 7) + ((idx >> 4) << 3);   // 0..31
    const int qt  = idx & 15;                      // 0..15 (128-q tiles)
    const int bi = bh >> 3, h = bh & 7;

    const _Float16* qhp = qh_ + ((size_t)bh * SEQ + qt * 128 + wave * 16) * HD;
    const _Float16* khp = kh_ + (size_t)bh * SEQ * HD;
    const _Float16* vp  = vt  + (size_t)bh * HD * SEQ;

    // Q B-frags, two groups 64 rows apart (pre-scaled by QSCALE)
    f16x8 qfa[2], qfb[2];
#pragma unroll
    for (int c = 0; c < 2; ++c) {
        qfa[c] = *(const f16x8*)&qhp[((size_t)m << 6) + c * 32 + (quad << 3)];
        qfb[c] = *(const f16x8*)&qhp[4096 + ((size_t)m << 6) + c * 32 + (quad << 3)];
    }

    f32x4 oacca[4], oaccb[4];   // [dt]: D[q=quad*4+rg][d=dt*16+m]
#pragma unroll
    for (int dt = 0; dt < 4; ++dt) {
        oacca[dt] = (f32x4){0.f, 0.f, 0.f, 0.f};
        oaccb[dt] = (f32x4){0.f, 0.f, 0.f, 0.f};
    }
    float la1 = 0.f, la2 = 0.f, lb1 = 0.f, lb2 = 0.f;

    // staging offsets: wave w stages K keys w*16+m and V rows d=w*16+m
    const size_t koff0 = ((size_t)(wave * 16 + m) << 6) + (quad << 3);
    const size_t koff1 = koff0 + 32;
    const size_t voff0 = ((size_t)(wave * 16 + m) << 11) + (quad << 3);
    const size_t voff1 = voff0 + 32;

    const h16x2 ones = {(__fp16)1.f, (__fp16)1.f};
    _Float16* pwa = PW[wave];
    _Float16* pwb = PW[wave] + 1024;
    const int rot = (m & 7) << 3;    // per-row key rotation, granularity 8

    auto tile = [&](const _Float16* KB, const _Float16* VB) {
        // ---- S^T = K·Q^T for both q-groups; kf read ONCE per pair ----
        f32x4 sva[4], svb[4];
#pragma unroll
        for (int nt = 0; nt < 4; ++nt) {
            f32x4 sa = (f32x4){0.f, 0.f, 0.f, 0.f};
            f32x4 sb = (f32x4){0.f, 0.f, 0.f, 0.f};
#pragma unroll
            for (int c = 0; c < 2; ++c) {
                f16x8 kf = *(const f16x8*)&KB[((c * 4 + nt) * 64 + lane) << 3];
                sa = MFMAH(kf, qfa[c], sa);
                sb = MFMAH(kf, qfb[c], sb);
            }
            sva[nt] = sa;   // [key=nt*16+quad*4+rg][q=m], log2 domain
            svb[nt] = sb;
        }

        // ---- V to regs (read ONCE, feeds both groups' PV) ----
        f16x8 vr0[4], vr1[4];
#pragma unroll
        for (int dt = 0; dt < 4; ++dt) {
            vr0[dt] = *(const f16x8*)&VB[((0 * 4 + dt) * 64 + lane) << 3];
            vr1[dt] = *(const f16x8*)&VB[((1 * 4 + dt) * 64 + lane) << 3];
        }

        // ---- softmax + pack + rotated PW write, both groups ----
#pragma unroll
        for (int nt = 0; nt < 4; ++nt) {
            union { unsigned int u[2]; f16x4 v; } pka, pkb;
#pragma unroll
            for (int i = 0; i < 2; ++i) {
                h16x2 ta = __builtin_amdgcn_cvt_pkrtz(EXP2(sva[nt][2 * i]),
                                                      EXP2(sva[nt][2 * i + 1]));
                h16x2 tb = __builtin_amdgcn_cvt_pkrtz(EXP2(svb[nt][2 * i]),
                                                      EXP2(svb[nt][2 * i + 1]));
                if (i == 0) { la1 = __builtin_amdgcn_fdot2(ta, ones, la1, false);
                              lb1 = __builtin_amdgcn_fdot2(tb, ones, lb1, false); }
                else        { la2 = __builtin_amdgcn_fdot2(ta, ones, la2, false);
                              lb2 = __builtin_amdgcn_fdot2(tb, ones, lb2, false); }
                union { h16x2 hh; unsigned int uu; } ca, cb;
                ca.hh = ta; cb.hh = tb;
                pka.u[i] = ca.uu; pkb.u[i] = cb.uu;
            }
            int pos = ((nt << 4) + (quad << 2) + rot) & 63;
            *(f16x4*)&pwa[(m << 6) + pos] = pka.v;
            *(f16x4*)&pwb[(m << 6) + pos] = pkb.v;
        }
        LGKM0();
        // ---- A-frags: single b128 each (8-aligned contiguous runs) ----
        f16x8 pf0a = *(const f16x8*)&pwa[(m << 6) + (((quad << 3) + rot) & 63)];
        f16x8 pf1a = *(const f16x8*)&pwa[(m << 6) + ((32 + (quad << 3) + rot) & 63)];
        f16x8 pf0b = *(const f16x8*)&pwb[(m << 6) + (((quad << 3) + rot) & 63)];
        f16x8 pf1b = *(const f16x8*)&pwb[(m << 6) + ((32 + (quad << 3) + rot) & 63)];

        // ---- O += P·V, both groups from the same V regs ----
#pragma unroll
        for (int dt = 0; dt < 4; ++dt) {
            oacca[dt] = MFMAH(pf0a, vr0[dt], oacca[dt]);
            oacca[dt] = MFMAH(pf1a, vr1[dt], oacca[dt]);
            oaccb[dt] = MFMAH(pf0b, vr0[dt], oaccb[dt]);
            oaccb[dt] = MFMAH(pf1b, vr1[dt], oaccb[dt]);
        }
    };

#define STAGE(b, st_) do { const size_t t0 = (size_t)(st_) * 2;               \
        async16(khp + koff0 + (t0 << 12), &KH[b][wave << 9]);                 \
        async16(khp + koff1 + (t0 << 12), &KH[b][(wave + 4) << 9]);           \
        async16(khp + koff0 + ((t0 + 1) << 12), &KH[b][4096 + (wave << 9)]);  \
        async16(khp + koff1 + ((t0 + 1) << 12), &KH[b][4096 + ((wave + 4) << 9)]); \
        async16(vp + voff0 + (t0 << 6), &VF[b][wave << 9]);                   \
        async16(vp + voff1 + (t0 << 6), &VF[b][(wave + 4) << 9]);             \
        async16(vp + voff0 + ((t0 + 1) << 6), &VF[b][4096 + (wave << 9)]);    \
        async16(vp + voff1 + ((t0 + 1) << 6), &VF[b][4096 + ((wave + 4) << 9)]); \
    } while (0)

    // ---- main loop: 16 super-tiles, double-buffered, counted vmcnt ----
    STAGE(0, 0);
#pragma unroll 1
    for (int st = 0; st < SEQ / 128; ++st) {
        const int b = st & 1;
        if (st + 1 < SEQ / 128) { STAGE(b ^ 1, st + 1); WAITVM(8); }
        else                    { WAITVM(0); }
        BAR();                       // super-tile st landed for all waves
        tile(&KH[b][0], &VF[b][0]);
        tile(&KH[b][4096], &VF[b][4096]);
        LGKM0();                     // my ds reads of buf b retired
        BAR();                       // everyone done -> b restageable
    }
#undef STAGE

    // ---- epilogue: per-group l reduce, normalize, fp16 store ----
#pragma unroll
    for (int g = 0; g < 2; ++g) {
        float lr = (g == 0) ? (la1 + la2) : (lb1 + lb2);
        lr += __shfl_xor(lr, 16);
        lr += __shfl_xor(lr, 32);
        float inv = 1.0f / lr;
        f32x4* oa = (g == 0) ? oacca : oaccb;
        size_t ob = ((size_t)(bi * SEQ + qt * 128 + g * 64 + wave * 16
                              + (quad << 2))) * DM + h * HD + m;
#pragma unroll
        for (int rg = 0; rg < 4; ++rg) {
            float il = __shfl(inv, (quad << 2) + rg, 16);
#pragma unroll
            for (int dt = 0; dt < 4; ++dt)
                oh[ob + (size_t)rg * DM + dt * 16] = (_Float16)(oa[dt][rg] * il);
        }
    }
}

// ---------------------------------------------------------------------------
// Kernel 3: out = attn @ Wo + bo, single-term fp16 MFMA + XCD row swizzle.
// R12: 3-stage pipeline (2-deep prefetch) — grid 256 = 1 block/CU, so
// in-wave pipelining is the only latency cover. LDS 48 KB.
// ---------------------------------------------------------------------------
__global__ __launch_bounds__(256)
void out_mfma(const _Float16* __restrict__ ah,
              const _Float16* __restrict__ wth,
              const float* __restrict__ bias, float* __restrict__ out)
{
    __shared__ __align__(16) _Float16 SM[24576];    // 48 KB: 3 x [A 8K|B 8K]

    const int tid  = threadIdx.x;
    const int lane = tid & 63;
    const int wave = tid >> 6;
    const int quad = lane >> 4;
    const int m    = lane & 15;
    const int wr   = wave >> 1, wc = wave & 1;

    // swizzle: XCD x owns row-blocks 8x..8x+7 (A slice 1MB + Wo-hi 0.5MB in L2)
    const int linear = blockIdx.x + (blockIdx.y << 6);   // 0..255
    const int xcd = linear & 7;
    const int r   = linear >> 3;                         // 0..31
    const int row0 = ((xcd << 3) + (r >> 2)) * 128;
    const int col0 = (r & 3) * 128;

    const size_t aoff0 = (size_t)(row0 + wave * 16 + m) * DM + (quad << 3);
    const size_t aoff1 = (size_t)(row0 + (wave + 4) * 16 + m) * DM + (quad << 3);
    const size_t boff0 = (size_t)(col0 + wave * 16 + m) * DM + (quad << 3);
    const size_t boff1 = (size_t)(col0 + (wave + 4) * 16 + m) * DM + (quad << 3);

    f32x4 acc[4][4];
#pragma unroll
    for (int i = 0; i < 4; ++i)
#pragma unroll
        for (int j = 0; j < 4; ++j) acc[i][j] = (f32x4){0.f, 0.f, 0.f, 0.f};

#define OSTAGE(b, kk) do {                                                    \
        async16(ah + aoff0 + (kk), &SM[(b) * 8192 + (wave << 9)]);            \
        async16(ah + aoff1 + (kk), &SM[(b) * 8192 + ((wave + 4) << 9)]);      \
        async16(wth + boff0 + (kk), &SM[(b) * 8192 + 4096 + (wave << 9)]);    \
        async16(wth + boff1 + (kk), &SM[(b) * 8192 + 4096 + ((wave + 4) << 9)]); \
    } while (0)

    OSTAGE(0, 0);
    OSTAGE(1, 32);
#pragma unroll 1
    for (int k0 = 0; k0 < DM; k0 += 32) {
        const int b = (k0 >> 5) % 3;
        if (k0 + 64 < DM)      { OSTAGE((b + 2) % 3, k0 + 64); WAITVM(8); }
        else if (k0 + 32 < DM) { WAITVM(4); }
        else                   { WAITVM(0); }
        BAR();

        const _Float16* Ah = &SM[b * 8192];
        const _Float16* Bh = Ah + 4096;
        f16x8 av[4], bvh[4];
#pragma unroll
        for (int t = 0; t < 4; ++t) {
            int ai  = ((((wr << 2) + t) << 6) + lane) << 3;
            int bi2 = ((((wc << 2) + t) << 6) + lane) << 3;
            av[t]  = *(const f16x8*)&Ah[ai];
            bvh[t] = *(const f16x8*)&Bh[bi2];
        }
#pragma unroll
        for (int rt = 0; rt < 4; ++rt)
#pragma unroll
            for (int ct = 0; ct < 4; ++ct)
                acc[rt][ct] = MFMAH(av[rt], bvh[ct], acc[rt][ct]);
        LGKM0();
        BAR();
    }
#undef OSTAGE

    // epilogue: LDS transpose -> coalesced float4 stores
    const int row0w = row0 + wr * 64;
    const int colw  = col0 + wc * 64;
    float bc[4];
#pragma unroll
    for (int ct = 0; ct < 4; ++ct) bc[ct] = bias[colw + (ct << 4) + m];

    float* tb = (float*)SM + wave * 1088;
    const int rr = lane >> 2, jj = lane & 3;
#pragma unroll
    for (int rt = 0; rt < 4; ++rt) {
#pragma unroll
        for (int ct = 0; ct < 4; ++ct)
#pragma unroll
            for (int rg = 0; rg < 4; ++rg)
                tb[((quad << 2) + rg) * 68 + (ct << 4) + m] =
                    acc[rt][ct][rg] + bc[ct];
        LGKM0();
        int n = row0w + (rt << 4) + rr;
#pragma unroll
        for (int i = 0; i < 4; ++i) {
            int c = (jj << 2) + (i << 4);
            *(float4*)&out[(size_t)n * DM + colw + c] =
                *(const float4*)&tb[rr * 68 + c];
        }
    }
}

// ---------------------------------------------------------------------------
extern "C" void kernel_launch(void* const* d_in, const int* in_sizes, int n_in,
                              void* d_out, int out_size, void* d_ws, size_t ws_size,
                              hipStream_t stream)
{
    const float* x    = (const float*)d_in[0];
    const float* Wqkv = (const float*)d_in[1];
    const float* bqkv = (const float*)d_in[2];
    const float* Wo   = (const float*)d_in[3];
    const float* bo   = (const float*)d_in[4];
    float* out = (float*)d_out;

    char* ws = (char*)d_ws;
    const size_t MB = 1024 * 1024;
    _Float16* qh    = (_Float16*)(ws);                       // 8 MB [B,H,S,64]
    _Float16* oh    = (_Float16*)(ws + 8 * MB);              // 8 MB [B,S,512]
    _Float16* kh    = (_Float16*)(ws + 16 * MB);             // 8 MB [B,H,S,64]
    _Float16* vT    = (_Float16*)(ws + 24 * MB);             // 8 MB [B,H,64,S]
    _Float16* xh    = (_Float16*)(ws + 32 * MB);             // 8 MB [8192][512]
    _Float16* wqt_h = (_Float16*)(ws + 40 * MB);             // 1.5 MB [1536][512]
    _Float16* wot_h = (_Float16*)(ws + 42 * MB);             // 0.5 MB [512][512]
    float2*   rtab  = (float2*)(ws + 43 * MB);               // 0.5 MB [2048][32]

    prep_all<<<2560, 256, 0, stream>>>(x, Wqkv, Wo, rtab, wqt_h, wot_h, xh);
    qkv_mfma<<<dim3(64, 12), 256, 0, stream>>>(xh, wqt_h, bqkv, rtab,
                                               qh, kh, vT);
    attn_mfma<<<dim3(16, 32), 256, 0, stream>>>(qh, kh, vT, oh);
    out_mfma<<<dim3(64, 4), 256, 0, stream>>>(oh, wot_h, bo, out);
}